// Round 1
// baseline (639.892 us; speedup 1.0000x reference)
//
#include <hip/hip_runtime.h>
#include <hip/hip_bf16.h>

#define BB   32
#define CIN  64
#define COUT 64
#define HH   64
#define WW   64
#define HW   4096
#define OFFC 18
#define KK2  9
#define II   576          // CIN * KK2
#define NP   32           // pixels per block in main kernel
#define SMPW (II + 8)     // padded smp row (bf16 elems): 584*2=1168B, 16B aligned, breaks 4-way bank conflict

typedef __attribute__((ext_vector_type(8))) unsigned short ushort8;

__device__ __forceinline__ float bf2f(unsigned short u) {
    union { unsigned int i; float f; } v;
    v.i = ((unsigned int)u) << 16;
    return v.f;
}

// ---------- x: [B][C][H][W] -> xT: [B][H][W][C] ----------
__global__ __launch_bounds__(256) void transpose_x(const float* __restrict__ x,
                                                   float* __restrict__ xT) {
    __shared__ float tile[64][65];
    const int bh = blockIdx.x;          // B*H = 2048
    const int b = bh >> 6, h = bh & 63;
    {
        const int w = threadIdx.x & 63, cg = threadIdx.x >> 6;
        #pragma unroll
        for (int c = cg; c < 64; c += 4)
            tile[c][w] = x[((b * 64 + c) * 64 + h) * 64 + w];   // coalesced over w
    }
    __syncthreads();
    {
        const int c = threadIdx.x & 63, wg = threadIdx.x >> 6;
        #pragma unroll
        for (int w = wg; w < 64; w += 4)
            xT[((b * 64 + h) * 64 + w) * 64 + c] = tile[c][w];  // coalesced over c
    }
}

// ---------- w_conv: [O][C][3][3] -> wT: [i=c*9+kk][O] ----------
__global__ __launch_bounds__(256) void transpose_w(const float* __restrict__ wc,
                                                   float* __restrict__ wT) {
    const int idx = blockIdx.x * 256 + threadIdx.x;   // 576*64 = 36864
    if (idx < II * COUT) {
        const int i = idx >> 6, o = idx & 63;
        wT[idx] = wc[o * II + i];
    }
}

// ---------- w_offset: [18][64][3][3] -> woffT: [c][ch][kk] ----------
__global__ __launch_bounds__(256) void transpose_woff(const float* __restrict__ w,
                                                      float* __restrict__ wt) {
    const int idx = blockIdx.x * 256 + threadIdx.x;   // 64*18*9 = 10368
    if (idx < CIN * OFFC * KK2) {
        const int kk = idx % KK2;
        const int r  = idx / KK2;
        const int ch = r % OFFC;
        const int c  = r / OFFC;
        wt[idx] = w[(ch * CIN + c) * KK2 + kk];
    }
}

// ---------- offset = conv3x3(x, w_offset) + b_offset ----------
// one thread per output pixel computes all 18 channels; weights wave-uniform -> s_load
__global__ __launch_bounds__(256) void offset_conv(const float* __restrict__ x,
                                                   const float* __restrict__ woffT,
                                                   const float* __restrict__ boff,
                                                   float* __restrict__ off) {
    const int pix = blockIdx.x * 256 + threadIdx.x;   // 131072
    const int b = pix >> 12, sp = pix & 4095;
    const int ho = sp >> 6, wo = sp & 63;

    float acc[OFFC];
    #pragma unroll
    for (int ch = 0; ch < OFFC; ++ch) acc[ch] = boff[ch];

    const float* xb = x + (size_t)b * CIN * HW;
    for (int c = 0; c < CIN; ++c) {
        float v[KK2];
        #pragma unroll
        for (int ki = 0; ki < 3; ++ki) {
            #pragma unroll
            for (int kj = 0; kj < 3; ++kj) {
                const int y = ho - 1 + ki, xx = wo - 1 + kj;
                const bool ok = ((unsigned)y < HH) & ((unsigned)xx < WW);
                v[ki * 3 + kj] = ok ? xb[(c * HH + y) * WW + xx] : 0.f;
            }
        }
        const float* wrow = woffT + c * (OFFC * KK2);   // uniform address -> scalar loads
        #pragma unroll
        for (int ch = 0; ch < OFFC; ++ch) {
            float a = acc[ch];
            #pragma unroll
            for (int kk = 0; kk < KK2; ++kk)
                a += v[kk] * wrow[ch * KK2 + kk];
            acc[ch] = a;
        }
    }
    #pragma unroll
    for (int ch = 0; ch < OFFC; ++ch)
        off[(b * OFFC + ch) * HW + sp] = acc[ch];       // coalesced over sp
}

// ---------- deformable conv main ----------
__global__ __launch_bounds__(256) void deform_main(const float* __restrict__ xT,
                                                   const float* __restrict__ off,
                                                   const float* __restrict__ wT,
                                                   const float* __restrict__ bconv,
                                                   float* __restrict__ out) {
    __shared__ __hip_bfloat16 smp[NP][SMPW];            // 37376 B
    __shared__ alignas(16) char metamem[NP * KK2 * 32]; // 9216 B: int4[288] + float4[288]; reused as outb
    int4*   mi = (int4*)metamem;
    float4* mw = (float4*)(metamem + NP * KK2 * 16);

    const int t = threadIdx.x;
    const int pix0 = blockIdx.x * NP;
    const int b = pix0 >> 12;                           // 4096 % NP == 0 -> whole block same image
    const int sp0 = pix0 & 4095;

    // ---- phase 0: sampling metadata (288 entries) ----
    for (int e = t; e < NP * KK2; e += 256) {
        const int p = e / KK2, kk = e - p * KK2;
        const int sp = sp0 + p;
        const int ho = sp >> 6, wo = sp & 63;
        const float dy = off[(b * OFFC + 2 * kk) * HW + sp];
        const float dx = off[(b * OFFC + 2 * kk + 1) * HW + sp];
        const int ki = kk / 3, kj = kk - ki * 3;
        const float py = (float)(ho - 1 + ki) + dy;
        const float px = (float)(wo - 1 + kj) + dx;
        const float y0f = floorf(py), x0f = floorf(px);
        const int y0 = (int)y0f, x0 = (int)x0f;
        const float wy1 = py - y0f, wx1 = px - x0f;
        const float wy0 = 1.f - wy1, wx0 = 1.f - wx1;
        const bool vy0 = (unsigned)y0 < HH;
        const bool vy1 = (unsigned)(y0 + 1) < HH;
        const bool vx0 = (unsigned)x0 < WW;
        const bool vx1 = (unsigned)(x0 + 1) < WW;
        int4 m;
        m.x = min(max(y0, 0), HH - 1);
        m.y = min(max(y0 + 1, 0), HH - 1);
        m.z = min(max(x0, 0), WW - 1);
        m.w = min(max(x0 + 1, 0), WW - 1);
        mi[e] = m;
        float4 w4;
        w4.x = (vy0 && vx0) ? wy0 * wx0 : 0.f;
        w4.y = (vy0 && vx1) ? wy0 * wx1 : 0.f;
        w4.z = (vy1 && vx0) ? wy1 * wx0 : 0.f;
        w4.w = (vy1 && vx1) ? wy1 * wx1 : 0.f;
        mw[e] = w4;
    }
    __syncthreads();

    // ---- phase 1: bilinear sampling -> smp (bf16) ----
    // lane = channel c (coalesced 256B gathers from channels-last xT); p uniform per wave
    {
        const int c = t & 63;
        const int pg = t >> 6;
        const float* xb = xT + (size_t)b * (HW * CIN);
        for (int q = 0; q < 8; ++q) {
            const int p = pg * 8 + q;
            #pragma unroll
            for (int kk = 0; kk < KK2; ++kk) {
                const int e = p * KK2 + kk;
                const int4 m = mi[e];           // broadcast ds_read_b128
                const float4 w4 = mw[e];
                const float* r0 = xb + m.x * (WW * CIN);
                const float* r1 = xb + m.y * (WW * CIN);
                const float v = w4.x * r0[m.z * CIN + c] + w4.y * r0[m.w * CIN + c]
                              + w4.z * r1[m.z * CIN + c] + w4.w * r1[m.w * CIN + c];
                smp[p][c * KK2 + kk] = __float2bfloat16(v);
            }
        }
    }
    __syncthreads();

    // ---- phase 2: C[p][o] = sum_i smp[p][i] * wT[i][o]  (32 x 64 x 576 per block) ----
    // thread: 2 pixels (pq, pq+16) x 4 outs (o0..o0+3) -> 8 accumulators
    const int o0 = (t & 15) * 4;
    const int pq = t >> 4;
    float a0[4], a1[4];
    #pragma unroll
    for (int j = 0; j < 4; ++j) { a0[j] = bconv[o0 + j]; a1[j] = a0[j]; }

    const ushort8* s0p = (const ushort8*)(&smp[pq][0]);
    const ushort8* s1p = (const ushort8*)(&smp[pq + 16][0]);
    const float4* wt4 = (const float4*)wT;
    const int wq = t & 15;

    for (int ch = 0; ch < II / 8; ++ch) {
        const ushort8 s0 = s0p[ch];             // broadcast ds_read_b128, 4 bank-disjoint groups
        const ushort8 s1 = s1p[ch];
        #pragma unroll
        for (int j = 0; j < 8; ++j) {
            const float4 w = wt4[(ch * 8 + j) * 16 + wq];   // coalesced 256B over wq
            const float f0 = bf2f(s0[j]);
            const float f1 = bf2f(s1[j]);
            a0[0] += f0 * w.x; a0[1] += f0 * w.y; a0[2] += f0 * w.z; a0[3] += f0 * w.w;
            a1[0] += f1 * w.x; a1[1] += f1 * w.y; a1[2] += f1 * w.z; a1[3] += f1 * w.w;
        }
    }

    // ---- epilogue: stage via LDS (reuse metamem) for coalesced stores ----
    float* outb = (float*)metamem;              // [COUT][NP+1] = 64*33 floats = 8448 B
    #pragma unroll
    for (int j = 0; j < 4; ++j) {
        outb[(o0 + j) * 33 + pq]      = a0[j];
        outb[(o0 + j) * 33 + pq + 16] = a1[j];
    }
    __syncthreads();
    {
        const int oo = t >> 2;
        const int pb = (t & 3) * 8;
        const float* lb = outb + oo * 33 + pb;
        float* gb = out + ((size_t)(b * COUT + oo)) * HW + sp0 + pb;
        float4 v0, v1;
        v0.x = lb[0]; v0.y = lb[1]; v0.z = lb[2]; v0.w = lb[3];
        v1.x = lb[4]; v1.y = lb[5]; v1.z = lb[6]; v1.w = lb[7];
        *(float4*)gb = v0;
        *(float4*)(gb + 4) = v1;
    }
}

extern "C" void kernel_launch(void* const* d_in, const int* in_sizes, int n_in,
                              void* d_out, int out_size, void* d_ws, size_t ws_size,
                              hipStream_t stream) {
    const float* x      = (const float*)d_in[0];
    const float* w_off  = (const float*)d_in[1];
    const float* b_off  = (const float*)d_in[2];
    const float* w_conv = (const float*)d_in[3];
    const float* b_conv = (const float*)d_in[4];
    float* out = (float*)d_out;

    // workspace layout (floats): xT 8388608 | off 2359296 | wT 36864 | woffT 10368  (~43.2 MB)
    float* xT    = (float*)d_ws;
    float* off   = xT + (size_t)BB * HW * CIN;
    float* wT    = off + (size_t)BB * OFFC * HW;
    float* woffT = wT + II * COUT;

    hipLaunchKernelGGL(transpose_x,   dim3(BB * HH), dim3(256), 0, stream, x, xT);
    hipLaunchKernelGGL(transpose_w,   dim3((II * COUT + 255) / 256), dim3(256), 0, stream, w_conv, wT);
    hipLaunchKernelGGL(transpose_woff,dim3((CIN * OFFC * KK2 + 255) / 256), dim3(256), 0, stream, w_off, woffT);
    hipLaunchKernelGGL(offset_conv,   dim3(BB * HW / 256), dim3(256), 0, stream, x, woffT, b_off, off);
    hipLaunchKernelGGL(deform_main,   dim3(BB * HW / NP), dim3(256), 0, stream, xT, off, wT, b_conv, out);
}

// Round 2
// 336.016 us; speedup vs baseline: 1.9044x; 1.9044x over previous
//
#include <hip/hip_runtime.h>
#include <hip/hip_bf16.h>

#define CIN  64
#define COUT 64
#define HH   64
#define WW   64
#define HW   4096
#define OFFC 18
#define KK2  9
#define II   576          // CIN * KK2
#define NP   32           // pixels per block
#define SMPW (II + 8)     // 584 bf16 -> row stride 1168 B = 73*16 B (odd multiple of 16B)
#define NKC  (II / 32)    // 18 k-chunks of 32 for 16x16x32 MFMA

typedef __attribute__((ext_vector_type(8))) short  short8;   // 8 x bf16 (A/B frag)
typedef __attribute__((ext_vector_type(4))) float  f32x4;    // C/D frag

// ---------- x: [B][C][H][W] -> xT: [B][H][W][C] ----------
__global__ __launch_bounds__(256) void transpose_x(const float* __restrict__ x,
                                                   float* __restrict__ xT) {
    __shared__ float tile[64][65];
    const int bh = blockIdx.x;          // B*H = 2048
    const int b = bh >> 6, h = bh & 63;
    {
        const int w = threadIdx.x & 63, cg = threadIdx.x >> 6;
        #pragma unroll
        for (int c = cg; c < 64; c += 4)
            tile[c][w] = x[((b * 64 + c) * 64 + h) * 64 + w];   // coalesced over w
    }
    __syncthreads();
    {
        const int c = threadIdx.x & 63, wg = threadIdx.x >> 6;
        #pragma unroll
        for (int w = wg; w < 64; w += 4)
            xT[((b * 64 + h) * 64 + w) * 64 + c] = tile[c][w];  // coalesced over c
    }
}

// ---------- w_conv [O=64][i=576] -> MFMA B-frag order: wmp[((nt*18+kc)*64+lane)*8+j] ----------
// B[k][n]: n = nt*16 + (lane&15), k = kc*32 + (lane>>4)*8 + j
__global__ __launch_bounds__(256) void pack_wmain(const float* __restrict__ wc,
                                                  __hip_bfloat16* __restrict__ wmp) {
    const int idx = blockIdx.x * 256 + threadIdx.x;   // 4*18*64*8 = 36864
    if (idx >= 4 * NKC * 64 * 8) return;
    const int j    = idx & 7;
    const int lane = (idx >> 3) & 63;
    const int kc   = (idx >> 9) % NKC;
    const int nt   = idx / (NKC * 512);
    const int o = nt * 16 + (lane & 15);
    const int k = kc * 32 + (lane >> 4) * 8 + j;
    wmp[idx] = __float2bfloat16(wc[o * II + k]);
}

// ---------- w_offset [ch=18][i=576] -> B-frag order, padded to 32 cols ----------
__global__ __launch_bounds__(256) void pack_woff(const float* __restrict__ w,
                                                 __hip_bfloat16* __restrict__ bop) {
    const int idx = blockIdx.x * 256 + threadIdx.x;   // 2*18*64*8 = 18432
    if (idx >= 2 * NKC * 64 * 8) return;
    const int j    = idx & 7;
    const int lane = (idx >> 3) & 63;
    const int kc   = (idx >> 9) % NKC;
    const int nt   = idx / (NKC * 512);
    const int ch = nt * 16 + (lane & 15);
    const int k  = kc * 32 + (lane >> 4) * 8 + j;
    bop[idx] = (ch < OFFC) ? __float2bfloat16(w[ch * II + k]) : __float2bfloat16(0.f);
}

// ---------- fused: offset conv (MFMA) + metadata + bilinear sampling + main GEMM (MFMA) ----------
__global__ __launch_bounds__(256, 3) void deform_fused(const float* __restrict__ xT,
                                                       const __hip_bfloat16* __restrict__ bop,
                                                       const __hip_bfloat16* __restrict__ wmp,
                                                       const float* __restrict__ boff,
                                                       const float* __restrict__ bconv,
                                                       float* __restrict__ out) {
    __shared__ __hip_bfloat16 smp[NP][SMPW];            // 37376 B: im2col A, then bilinear samples
    __shared__ alignas(16) char metamem[NP * KK2 * 32]; // 9216 B: int4[288]+float4[288]; reused as outb
    __shared__ float offs[NP][20];                      // 2560 B: per-pixel 18 offsets (padded)
    int4*   mi = (int4*)metamem;
    float4* mw = (float4*)(metamem + NP * KK2 * 16);

    const int t = threadIdx.x;
    const int wave = t >> 6, lane = t & 63;
    const int pix0 = blockIdx.x * NP;
    const int b = pix0 >> 12;                           // whole block in one image
    const int sp0 = pix0 & 4095;
    const float* xb = xT + (size_t)b * (HW * CIN);

    // ---- phase A: integer-grid im2col -> smp (bf16); lane = channel, coalesced ----
    {
        const int c = lane;
        for (int q = 0; q < 8; ++q) {
            const int p = wave * 8 + q;
            const int sp = sp0 + p;
            const int ho = sp >> 6, wo = sp & 63;
            #pragma unroll
            for (int kk = 0; kk < KK2; ++kk) {
                const int ki = kk / 3, kj = kk - ki * 3;
                const int y = ho - 1 + ki, xx = wo - 1 + kj;
                const bool ok = ((unsigned)y < HH) & ((unsigned)xx < WW);
                const float v = ok ? xb[(y * WW + xx) * CIN + c] : 0.f;
                smp[p][c * KK2 + kk] = __float2bfloat16(v);
            }
        }
    }
    __syncthreads();

    // ---- phase B: offset GEMM (32 x 576 @ 576 x 32padded), 1 tile per wave ----
    {
        const int mtB = wave & 1, ntB = wave >> 1;
        f32x4 oa = {0.f, 0.f, 0.f, 0.f};
        const char* abase = (const char*)&smp[mtB * 16 + (lane & 15)][0] + (lane >> 4) * 16;
        const short8* bp = (const short8*)bop + ntB * NKC * 64 + lane;
        #pragma unroll
        for (int kc = 0; kc < NKC; ++kc) {
            const short8 a  = *(const short8*)(abase + kc * 64);   // ds_read_b128
            const short8 bo = bp[kc * 64];                         // coalesced global (L2-hot)
            oa = __builtin_amdgcn_mfma_f32_16x16x32_bf16(a, bo, oa, 0, 0, 0);
        }
        const int ch = ntB * 16 + (lane & 15);                     // D: col=lane&15, row=quad*4+r
        if (ch < OFFC) {
            const float bias = boff[ch];
            const int pr = mtB * 16 + (lane >> 4) * 4;
            #pragma unroll
            for (int r = 0; r < 4; ++r)
                offs[pr + r][ch] = oa[r] + bias;
        }
    }
    __syncthreads();

    // ---- phase C: sampling metadata (288 entries) ----
    for (int e = t; e < NP * KK2; e += 256) {
        const int p = e / KK2, kk = e - p * KK2;
        const int sp = sp0 + p;
        const int ho = sp >> 6, wo = sp & 63;
        const float dy = offs[p][2 * kk];
        const float dx = offs[p][2 * kk + 1];
        const int ki = kk / 3, kj = kk - ki * 3;
        const float py = (float)(ho - 1 + ki) + dy;
        const float px = (float)(wo - 1 + kj) + dx;
        const float y0f = floorf(py), x0f = floorf(px);
        const int y0 = (int)y0f, x0 = (int)x0f;
        const float wy1 = py - y0f, wx1 = px - x0f;
        const float wy0 = 1.f - wy1, wx0 = 1.f - wx1;
        const bool vy0 = (unsigned)y0 < HH;
        const bool vy1 = (unsigned)(y0 + 1) < HH;
        const bool vx0 = (unsigned)x0 < WW;
        const bool vx1 = (unsigned)(x0 + 1) < WW;
        int4 m;
        m.x = min(max(y0, 0), HH - 1);
        m.y = min(max(y0 + 1, 0), HH - 1);
        m.z = min(max(x0, 0), WW - 1);
        m.w = min(max(x0 + 1, 0), WW - 1);
        mi[e] = m;
        float4 w4;
        w4.x = (vy0 && vx0) ? wy0 * wx0 : 0.f;
        w4.y = (vy0 && vx1) ? wy0 * wx1 : 0.f;
        w4.z = (vy1 && vx0) ? wy1 * wx0 : 0.f;
        w4.w = (vy1 && vx1) ? wy1 * wx1 : 0.f;
        mw[e] = w4;
    }
    __syncthreads();

    // ---- phase D: preload main-GEMM B frags (block-invariant, overlaps gathers), bilinear -> smp ----
    short8 bw[NKC];                                     // wave's 16-col N-tile, 72 VGPRs
    {
        const short8* wp = (const short8*)wmp + wave * NKC * 64 + lane;
        #pragma unroll
        for (int kc = 0; kc < NKC; ++kc) bw[kc] = wp[kc * 64];
    }
    {
        const int c = lane;
        for (int q = 0; q < 8; ++q) {
            const int p = wave * 8 + q;
            #pragma unroll
            for (int kk = 0; kk < KK2; ++kk) {
                const int e = p * KK2 + kk;
                const int4 m = mi[e];                   // broadcast ds_read_b128
                const float4 w4 = mw[e];
                const float* r0 = xb + m.x * (WW * CIN);
                const float* r1 = xb + m.y * (WW * CIN);
                const float v = w4.x * r0[m.z * CIN + c] + w4.y * r0[m.w * CIN + c]
                              + w4.z * r1[m.z * CIN + c] + w4.w * r1[m.w * CIN + c];
                smp[p][c * KK2 + kk] = __float2bfloat16(v);
            }
        }
    }
    __syncthreads();

    // ---- phase E: main GEMM 32 x 576 @ 576 x 64; wave = N-tile, 2 M-tiles ----
    f32x4 acc0 = {0.f, 0.f, 0.f, 0.f}, acc1 = {0.f, 0.f, 0.f, 0.f};
    {
        const char* a0base = (const char*)&smp[lane & 15][0]      + (lane >> 4) * 16;
        const char* a1base = (const char*)&smp[16 + (lane & 15)][0] + (lane >> 4) * 16;
        #pragma unroll
        for (int kc = 0; kc < NKC; ++kc) {
            const short8 a0 = *(const short8*)(a0base + kc * 64);
            const short8 a1 = *(const short8*)(a1base + kc * 64);
            acc0 = __builtin_amdgcn_mfma_f32_16x16x32_bf16(a0, bw[kc], acc0, 0, 0, 0);
            acc1 = __builtin_amdgcn_mfma_f32_16x16x32_bf16(a1, bw[kc], acc1, 0, 0, 0);
        }
    }

    // ---- phase F: epilogue via LDS (reuse metamem) for coalesced stores ----
    {
        float* outb = (float*)metamem;                  // [COUT][NP+1] = 64*33 floats
        const int o = wave * 16 + (lane & 15);
        const float bias = bconv[o];
        const int pr = (lane >> 4) * 4;
        #pragma unroll
        for (int r = 0; r < 4; ++r) {
            outb[o * 33 + pr + r]      = acc0[r] + bias;
            outb[o * 33 + pr + r + 16] = acc1[r] + bias;
        }
    }
    __syncthreads();
    {
        const float* outb = (const float*)metamem;
        const int oo = t >> 2, pb = (t & 3) * 8;
        const float* lb = outb + oo * 33 + pb;
        float* gb = out + ((size_t)(b * COUT + oo)) * HW + sp0 + pb;
        float4 v0, v1;
        v0.x = lb[0]; v0.y = lb[1]; v0.z = lb[2]; v0.w = lb[3];
        v1.x = lb[4]; v1.y = lb[5]; v1.z = lb[6]; v1.w = lb[7];
        *(float4*)gb = v0;
        *(float4*)(gb + 4) = v1;
    }
}

extern "C" void kernel_launch(void* const* d_in, const int* in_sizes, int n_in,
                              void* d_out, int out_size, void* d_ws, size_t ws_size,
                              hipStream_t stream) {
    const float* x      = (const float*)d_in[0];
    const float* w_off  = (const float*)d_in[1];
    const float* b_off  = (const float*)d_in[2];
    const float* w_conv = (const float*)d_in[3];
    const float* b_conv = (const float*)d_in[4];
    float* out = (float*)d_out;

    // ws layout: xT (32*4096*64 f32 = 33.55 MB) | wmp (36864 bf16) | bop (18432 bf16)
    float* xT = (float*)d_ws;
    __hip_bfloat16* wmp = (__hip_bfloat16*)(xT + (size_t)32 * HW * CIN);
    __hip_bfloat16* bop = wmp + 4 * NKC * 64 * 8;

    hipLaunchKernelGGL(transpose_x, dim3(32 * HH), dim3(256), 0, stream, x, xT);
    hipLaunchKernelGGL(pack_wmain,  dim3((4 * NKC * 512 + 255) / 256), dim3(256), 0, stream, w_conv, wmp);
    hipLaunchKernelGGL(pack_woff,   dim3((2 * NKC * 512 + 255) / 256), dim3(256), 0, stream, w_off, bop);
    hipLaunchKernelGGL(deform_fused, dim3(32 * HW / NP), dim3(256), 0, stream,
                       xT, bop, wmp, b_off, b_conv, out);
}

// Round 3
// 252.353 us; speedup vs baseline: 2.5357x; 1.3315x over previous
//
#include <hip/hip_runtime.h>
#include <hip/hip_bf16.h>

#define CIN  64
#define COUT 64
#define HH   64
#define WW   64
#define HW   4096
#define OFFC 18
#define KK2  9
#define II   576          // CIN * KK2
#define NP   32           // pixels per block
#define SMPW (II + 8)     // 584 bf16 -> row stride 1168 B (odd multiple of 16B: 2-way-free b128 reads)
#define NKC  (II / 32)    // 18 k-chunks for 16x16x32 MFMA
#define IMGB (HW * CIN * 2)   // bytes per bf16 image = 524288

typedef __attribute__((ext_vector_type(8))) short  short8;   // 8 x bf16 (A/B frag)
typedef __attribute__((ext_vector_type(4))) float  f32x4;    // C/D frag

__device__ __forceinline__ float u2f(unsigned int u) {
    union { unsigned int i; float f; } v; v.i = u; return v.f;
}

// ---------- x: [B][C][H][W] f32 -> xT: [B][H][W][C] bf16 ----------
__global__ __launch_bounds__(256) void transpose_x(const float* __restrict__ x,
                                                   __hip_bfloat16* __restrict__ xT) {
    __shared__ float tile[64][65];
    const int bh = blockIdx.x;          // B*H = 2048
    const int b = bh >> 6, h = bh & 63;
    {
        const int w = threadIdx.x & 63, cg = threadIdx.x >> 6;
        #pragma unroll
        for (int c = cg; c < 64; c += 4)
            tile[c][w] = x[((b * 64 + c) * 64 + h) * 64 + w];   // coalesced over w
    }
    __syncthreads();
    {
        const int c = threadIdx.x & 63, wg = threadIdx.x >> 6;
        #pragma unroll
        for (int w = wg; w < 64; w += 4)
            xT[((b * 64 + h) * 64 + w) * 64 + c] = __float2bfloat16(tile[c][w]);
    }
}

// smp k-ordering: s = kk*64 + c  (so phase-D stores are contiguous b32 across lanes).
// Weight packs below apply the matching permutation: frag pos s -> original k = c*9 + kk.

// ---------- w_conv [O=64][C=64][3][3] -> B-frag order ----------
__global__ __launch_bounds__(256) void pack_wmain(const float* __restrict__ wc,
                                                  __hip_bfloat16* __restrict__ wmp) {
    const int idx = blockIdx.x * 256 + threadIdx.x;   // 4*18*64*8 = 36864
    if (idx >= 4 * NKC * 64 * 8) return;
    const int j    = idx & 7;
    const int lane = (idx >> 3) & 63;
    const int kc   = (idx >> 9) % NKC;
    const int nt   = idx / (NKC * 512);
    const int o  = nt * 16 + (lane & 15);
    const int ks = kc * 32 + (lane >> 4) * 8 + j;     // fragment k position = smp s-index
    const int c  = ks & 63, kk = ks >> 6;
    wmp[idx] = __float2bfloat16(wc[(o * CIN + c) * KK2 + kk]);
}

// ---------- w_offset [18][64][3][3] -> B-frag order, padded to 32 cols ----------
__global__ __launch_bounds__(256) void pack_woff(const float* __restrict__ w,
                                                 __hip_bfloat16* __restrict__ bop) {
    const int idx = blockIdx.x * 256 + threadIdx.x;   // 2*18*64*8 = 18432
    if (idx >= 2 * NKC * 64 * 8) return;
    const int j    = idx & 7;
    const int lane = (idx >> 3) & 63;
    const int kc   = (idx >> 9) % NKC;
    const int nt   = idx / (NKC * 512);
    const int ch = nt * 16 + (lane & 15);
    const int ks = kc * 32 + (lane >> 4) * 8 + j;
    const int c  = ks & 63, kk = ks >> 6;
    bop[idx] = (ch < OFFC) ? __float2bfloat16(w[(ch * CIN + c) * KK2 + kk])
                           : __float2bfloat16(0.f);
}

// ---------- fused: offset conv (MFMA) + metadata + bilinear sampling + main GEMM (MFMA) ----------
__global__ __launch_bounds__(256, 4) void deform_fused(const __hip_bfloat16* __restrict__ xT,
                                                       const __hip_bfloat16* __restrict__ bop,
                                                       const __hip_bfloat16* __restrict__ wmp,
                                                       const float* __restrict__ boff,
                                                       const float* __restrict__ bconv,
                                                       float* __restrict__ out) {
    __shared__ __hip_bfloat16 smp[NP][SMPW];      // 37376 B; aliased as outb in epilogue
    __shared__ alignas(16) char meta[3456];       // mbase[288] int | mwts[288] uint2; aliased by offs[32][20]
    int*   mbase = (int*)meta;
    uint2* mwts  = (uint2*)(meta + 1152);
    float* offs  = (float*)meta;                  // phase B->C only (reg-staged before meta writes)

    const int t = threadIdx.x;
    const int wave = t >> 6, lane = t & 63;
    const int pix0 = blockIdx.x * NP;
    const int b = pix0 >> 12;                     // whole block in one image, one row (ho uniform)
    const int sp0 = pix0 & 4095;
    const char* xbB = (const char*)xT + (size_t)b * IMGB;

    // ---- phase A: integer-grid im2col -> smp (bf16 passthrough, wide loads) ----
    {
        const int j  = lane >> 4;                 // col slot 0..3
        const int cg = lane & 15;                 // channel group (4 ch)
        for (int q = 0; q < 8; ++q) {
            const int p = wave * 8 + q;
            const int sp = sp0 + p;
            const int ho = sp >> 6, wo = sp & 63; // uniform across wave
            const int cb = min(max(wo - 1, 0), 61);
            const int d  = cb - wo + 1;           // {-1,0,1}, wave-uniform
            #pragma unroll
            for (int ki = 0; ki < 3; ++ki) {
                const int y  = ho - 1 + ki;
                const int yl = min(max(y, 0), 63);
                // 4 cols x 64 ch bf16 = 512 B; lane: col cb+j, chs 4cg..4cg+3
                uint2 v = *(const uint2*)(xbB + (yl * 64 + cb) * 128 + lane * 8);
                if (d != 0) {                     // edge pixel: realign slots to kj
                    const int src = lane - 16 * d;
                    v.x = (unsigned)__shfl((int)v.x, src, 64);
                    v.y = (unsigned)__shfl((int)v.y, src, 64);
                }
                const int kj = j;                 // target tap (j==3 -> no write)
                const int nc = wo - 1 + kj;       // true column for this tap
                const bool ok = ((unsigned)y < HH) & ((unsigned)nc < WW);
                if (kj < 3) {
                    uint2 w2; w2.x = ok ? v.x : 0u; w2.y = ok ? v.y : 0u;
                    *(uint2*)((char*)&smp[p][0] + (ki * 3 + kj) * 128 + cg * 8) = w2;
                }
            }
        }
    }
    __syncthreads();

    // ---- phase B: offset GEMM (32 x 576 @ 576 x 32padded), 1 MFMA tile per wave ----
    {
        const int mtB = wave & 1, ntB = wave >> 1;
        f32x4 oa = {0.f, 0.f, 0.f, 0.f};
        const char* abase = (const char*)&smp[mtB * 16 + (lane & 15)][0] + (lane >> 4) * 16;
        const short8* bp = (const short8*)bop + ntB * NKC * 64 + lane;
        #pragma unroll
        for (int kc = 0; kc < NKC; ++kc) {
            const short8 a  = *(const short8*)(abase + kc * 64);   // ds_read_b128
            const short8 bo2 = bp[kc * 64];                        // coalesced global (L2-hot)
            oa = __builtin_amdgcn_mfma_f32_16x16x32_bf16(a, bo2, oa, 0, 0, 0);
        }
        const int ch = ntB * 16 + (lane & 15);    // D: col=lane&15, row=quad*4+r
        if (ch < OFFC) {
            const float bias = boff[ch];
            const int pr = mtB * 16 + (lane >> 4) * 4;
            #pragma unroll
            for (int r = 0; r < 4; ++r)
                offs[(pr + r) * 20 + ch] = oa[r] + bias;
        }
    }
    __syncthreads();

    // ---- phase C: folded bilinear metadata (288 taps); offs/meta alias -> reg-stage ----
    {
        int  bo_r[2]; unsigned int lo_r[2], hi_r[2];
        #pragma unroll
        for (int i = 0; i < 2; ++i) {
            const int e = t + i * 256;
            if (e < NP * KK2) {
                const int p = e / KK2, kk = e - p * KK2;
                const int sp = sp0 + p;
                const int ho = sp >> 6, wo = sp & 63;
                const float dy = offs[p * 20 + 2 * kk];
                const float dx = offs[p * 20 + 2 * kk + 1];
                const int ki = kk / 3, kj = kk - ki * 3;
                const float py = (float)(ho - 1 + ki) + dy;
                const float px = (float)(wo - 1 + kj) + dx;
                const float y0f = floorf(py), x0f = floorf(px);
                const int y0 = (int)y0f, x0 = (int)x0f;
                const float wy1 = py - y0f, wx1 = px - x0f;
                const float wy0 = 1.f - wy1, wx0 = 1.f - wx1;
                const int yb = min(max(y0, 0), HH - 2);
                const int zb = min(max(x0, 0), WW - 2);
                // fold validity+clamping into per-axis slot weights
                const float vy0 = ((unsigned)y0 < HH) ? wy0 : 0.f;
                const float vy1 = ((unsigned)(y0 + 1) < HH) ? wy1 : 0.f;
                const float vx0 = ((unsigned)x0 < WW) ? wx0 : 0.f;
                const float vx1 = ((unsigned)(x0 + 1) < WW) ? wx1 : 0.f;
                const float t0 = (y0 == yb ? vy0 : 0.f) + (y0 + 1 == yb ? vy1 : 0.f);
                const float t1 = (y0 == yb + 1 ? vy0 : 0.f) + (y0 + 1 == yb + 1 ? vy1 : 0.f);
                const float u0 = (x0 == zb ? vx0 : 0.f) + (x0 + 1 == zb ? vx1 : 0.f);
                const float u1 = (x0 == zb + 1 ? vx0 : 0.f) + (x0 + 1 == zb + 1 ? vx1 : 0.f);
                bo_r[i] = (yb * 64 + zb) * 128;   // byte offset into bf16 image
                union { unsigned int u; _Float16 h[2]; } c0, c1;
                c0.h[0] = (_Float16)(t0 * u0); c0.h[1] = (_Float16)(t1 * u0);
                c1.h[0] = (_Float16)(t0 * u1); c1.h[1] = (_Float16)(t1 * u1);
                lo_r[i] = c0.u; hi_r[i] = c1.u;
            }
        }
        __syncthreads();                          // all offs reads done before meta overwrite
        #pragma unroll
        for (int i = 0; i < 2; ++i) {
            const int e = t + i * 256;
            if (e < NP * KK2) {
                mbase[e] = bo_r[i];
                uint2 w2; w2.x = lo_r[i]; w2.y = hi_r[i];
                mwts[e] = w2;
            }
        }
    }
    __syncthreads();

    // ---- phase D: preload B frags (hidden behind gathers), bilinear sampling -> smp ----
    short8 bw[NKC];                               // wave's 16-col N-tile, 72 VGPRs
    {
        const short8* wp = (const short8*)wmp + wave * NKC * 64 + lane;
        #pragma unroll
        for (int kc = 0; kc < NKC; ++kc) bw[kc] = wp[kc * 64];
    }
    {
        const int li = lane & 31;
        const bool lowHalf = (lane < 32);
        for (int q = 0; q < 8; ++q) {
            const int p = wave * 8 + q;
            #pragma unroll
            for (int kk = 0; kk < KK2; ++kk) {
                const int e = p * KK2 + kk;
                const int bo = mbase[e];          // broadcast ds_read
                const uint2 wts = mwts[e];
                const unsigned int wsel = lowHalf ? wts.x : wts.y;
                union { unsigned int u; _Float16 h[2]; } cv; cv.u = wsel;
                const float tu0 = (float)cv.h[0], tu1 = (float)cv.h[1];
                // rows yb, yb+1: 256 B each covers cols zb & zb+1 x 64 ch (bf16)
                const unsigned int a  = *(const unsigned int*)(xbB + bo + lane * 4);
                const unsigned int b2 = *(const unsigned int*)(xbB + bo + 8192 + lane * 4);
                const float a_lo = u2f(a << 16),  a_hi = u2f(a & 0xffff0000u);
                const float b_lo = u2f(b2 << 16), b_hi = u2f(b2 & 0xffff0000u);
                float p0 = tu0 * a_lo + tu1 * b_lo;
                float p1 = tu0 * a_hi + tu1 * b_hi;
                p0 += __shfl_xor(p0, 32, 64);     // col zb + col zb+1
                p1 += __shfl_xor(p1, 32, 64);
                if (lowHalf) {
                    __hip_bfloat162 pk;
                    pk.x = __float2bfloat16(p0);
                    pk.y = __float2bfloat16(p1);
                    *(__hip_bfloat162*)((char*)&smp[p][0] + kk * 128 + li * 4) = pk;
                }
            }
        }
    }
    __syncthreads();

    // ---- phase E: main GEMM 32 x 576 @ 576 x 64; wave = N-tile, 2 M-tiles ----
    f32x4 acc0 = {0.f, 0.f, 0.f, 0.f}, acc1 = {0.f, 0.f, 0.f, 0.f};
    {
        const char* a0base = (const char*)&smp[lane & 15][0]        + (lane >> 4) * 16;
        const char* a1base = (const char*)&smp[16 + (lane & 15)][0] + (lane >> 4) * 16;
        #pragma unroll
        for (int kc = 0; kc < NKC; ++kc) {
            const short8 a0 = *(const short8*)(a0base + kc * 64);
            const short8 a1 = *(const short8*)(a1base + kc * 64);
            acc0 = __builtin_amdgcn_mfma_f32_16x16x32_bf16(a0, bw[kc], acc0, 0, 0, 0);
            acc1 = __builtin_amdgcn_mfma_f32_16x16x32_bf16(a1, bw[kc], acc1, 0, 0, 0);
        }
    }
    __syncthreads();                              // smp reads done; safe to alias as outb

    // ---- phase F: epilogue via LDS (aliases smp) for coalesced stores ----
    {
        float* outb = (float*)&smp[0][0];         // [COUT][33] floats = 8448 B
        const int o = wave * 16 + (lane & 15);
        const float bias = bconv[o];
        const int pr = (lane >> 4) * 4;
        #pragma unroll
        for (int r = 0; r < 4; ++r) {
            outb[o * 33 + pr + r]      = acc0[r] + bias;
            outb[o * 33 + pr + r + 16] = acc1[r] + bias;
        }
    }
    __syncthreads();
    {
        const float* outb = (const float*)&smp[0][0];
        const int oo = t >> 2, pb = (t & 3) * 8;
        const float* lb = outb + oo * 33 + pb;
        float* gb = out + ((size_t)(b * COUT + oo)) * HW + sp0 + pb;
        float4 v0, v1;
        v0.x = lb[0]; v0.y = lb[1]; v0.z = lb[2]; v0.w = lb[3];
        v1.x = lb[4]; v1.y = lb[5]; v1.z = lb[6]; v1.w = lb[7];
        *(float4*)gb = v0;
        *(float4*)(gb + 4) = v1;
    }
}

extern "C" void kernel_launch(void* const* d_in, const int* in_sizes, int n_in,
                              void* d_out, int out_size, void* d_ws, size_t ws_size,
                              hipStream_t stream) {
    const float* x      = (const float*)d_in[0];
    const float* w_off  = (const float*)d_in[1];
    const float* b_off  = (const float*)d_in[2];
    const float* w_conv = (const float*)d_in[3];
    const float* b_conv = (const float*)d_in[4];
    float* out = (float*)d_out;

    // ws layout: xT bf16 (32*4096*64 = 16.78 MB) | wmp (36864 bf16) | bop (18432 bf16)
    __hip_bfloat16* xT  = (__hip_bfloat16*)d_ws;
    __hip_bfloat16* wmp = xT + (size_t)32 * HW * CIN;
    __hip_bfloat16* bop = wmp + 4 * NKC * 64 * 8;

    hipLaunchKernelGGL(transpose_x, dim3(32 * HH), dim3(256), 0, stream, x, xT);
    hipLaunchKernelGGL(pack_wmain,  dim3((4 * NKC * 512 + 255) / 256), dim3(256), 0, stream, w_conv, wmp);
    hipLaunchKernelGGL(pack_woff,   dim3((2 * NKC * 512 + 255) / 256), dim3(256), 0, stream, w_off, bop);
    hipLaunchKernelGGL(deform_fused, dim3(32 * HW / NP), dim3(256), 0, stream,
                       xT, bop, wmp, b_off, b_conv, out);
}

// Round 4
// 228.561 us; speedup vs baseline: 2.7997x; 1.1041x over previous
//
#include <hip/hip_runtime.h>
#include <hip/hip_bf16.h>

#define CIN  64
#define COUT 64
#define HH   64
#define WW   64
#define HW   4096
#define OFFC 18
#define KK2  9
#define II   576            // CIN * KK2
#define NP   16             // pixels per block in main kernel
#define SMPW (II + 8)       // 584 bf16 -> row stride 1168 B (odd multiple of 16B)
#define NKC  (II / 32)      // 18 k-chunks for 16x16x32 MFMA
#define IMGB (HW * CIN * 2) // bytes per bf16 image = 524288

typedef __attribute__((ext_vector_type(8))) short  short8;   // 8 x bf16 (A/B frag)
typedef __attribute__((ext_vector_type(4))) float  f32x4;    // C/D frag

__device__ __forceinline__ float u2f(unsigned int u) {
    union { unsigned int i; float f; } v; v.i = u; return v.f;
}
__device__ __forceinline__ short8 as_short8(uint4 u) {
    union { uint4 a; short8 b; } v; v.a = u; return v.b;
}

// ---------- x: [B][C][H][W] f32 -> xT: [B][H][W][C] bf16 ----------
__global__ __launch_bounds__(256) void transpose_x(const float* __restrict__ x,
                                                   __hip_bfloat16* __restrict__ xT) {
    __shared__ float tile[64][65];
    const int bh = blockIdx.x;          // B*H = 2048
    const int b = bh >> 6, h = bh & 63;
    {
        const int w = threadIdx.x & 63, cg = threadIdx.x >> 6;
        #pragma unroll
        for (int c = cg; c < 64; c += 4)
            tile[c][w] = x[((b * 64 + c) * 64 + h) * 64 + w];   // coalesced over w
    }
    __syncthreads();
    {
        const int c = threadIdx.x & 63, wg = threadIdx.x >> 6;
        #pragma unroll
        for (int w = wg; w < 64; w += 4)
            xT[((b * 64 + h) * 64 + w) * 64 + c] = __float2bfloat16(tile[c][w]);
    }
}

// smp k-ordering: s = kk*64 + c. Weight packs apply matching permutation.

// ---------- w_conv [O=64][C=64][3][3] -> B-frag order ----------
__global__ __launch_bounds__(256) void pack_wmain(const float* __restrict__ wc,
                                                  __hip_bfloat16* __restrict__ wmp) {
    const int idx = blockIdx.x * 256 + threadIdx.x;   // 4*18*64*8 = 36864
    if (idx >= 4 * NKC * 64 * 8) return;
    const int j    = idx & 7;
    const int lane = (idx >> 3) & 63;
    const int kc   = (idx >> 9) % NKC;
    const int nt   = idx / (NKC * 512);
    const int o  = nt * 16 + (lane & 15);
    const int ks = kc * 32 + (lane >> 4) * 8 + j;     // smp s-index
    const int c  = ks & 63, kk = ks >> 6;
    wmp[idx] = __float2bfloat16(wc[(o * CIN + c) * KK2 + kk]);
}

// ---------- w_offset [18][64][3][3] -> B-frag order, padded to 32 cols ----------
__global__ __launch_bounds__(256) void pack_woff(const float* __restrict__ w,
                                                 __hip_bfloat16* __restrict__ bop) {
    const int idx = blockIdx.x * 256 + threadIdx.x;   // 2*18*64*8 = 18432
    if (idx >= 2 * NKC * 64 * 8) return;
    const int j    = idx & 7;
    const int lane = (idx >> 3) & 63;
    const int kc   = (idx >> 9) % NKC;
    const int nt   = idx / (NKC * 512);
    const int ch = nt * 16 + (lane & 15);
    const int ks = kc * 32 + (lane >> 4) * 8 + j;
    const int c  = ks & 63, kk = ks >> 6;
    bop[idx] = (ch < OFFC) ? __float2bfloat16(w[(ch * CIN + c) * KK2 + kk])
                           : __float2bfloat16(0.f);
}

// ---------- kernel 1: offset conv (direct, MFMA from global) + folded metadata ----------
// block = one image row (64 pixels), 4 waves; wave = 16-pixel M-tile x 32(18) outs
__global__ __launch_bounds__(256) void offset_meta(const __hip_bfloat16* __restrict__ xT,
                                                   const __hip_bfloat16* __restrict__ bop,
                                                   const float* __restrict__ boff,
                                                   uint4* __restrict__ gmeta) {
    __shared__ float offs[64][20];                    // 5120 B
    const int t = threadIdx.x;
    const int wave = t >> 6, lane = t & 63;
    const int bh = blockIdx.x;                        // b*64 + ho
    const int b = bh >> 6, ho = bh & 63;
    const char* xbB = (const char*)xT + (size_t)b * IMGB;
    const int wo0 = wave * 16;
    const int m = lane & 15, quad = lane >> 4;

    f32x4 acc0 = {0.f, 0.f, 0.f, 0.f};               // N-tile 0: ch 0..15
    f32x4 acc1 = {0.f, 0.f, 0.f, 0.f};               // N-tile 1: ch 16,17
    const short8* bp = (const short8*)bop;
    #pragma unroll
    for (int kk = 0; kk < KK2; ++kk) {
        const int ki = kk / 3, kj = kk - ki * 3;
        const int y = ho - 1 + ki;                    // wave-uniform
        if ((unsigned)y < HH) {
            const int col = wo0 + m + kj - 1;
            const int ccl = min(max(col, 0), WW - 1);
            const bool ok = (unsigned)col < WW;
            const char* base = xbB + (y * 64 + ccl) * 128 + quad * 16;
            #pragma unroll
            for (int h = 0; h < 2; ++h) {
                uint4 av = *(const uint4*)(base + h * 64);
                if (!ok) { av.x = 0u; av.y = 0u; av.z = 0u; av.w = 0u; }
                const short8 a = as_short8(av);
                const int kc = 2 * kk + h;
                const short8 b0 = bp[(kc * 64 + lane)];
                const short8 b1 = bp[((NKC + kc) * 64 + lane)];
                acc0 = __builtin_amdgcn_mfma_f32_16x16x32_bf16(a, b0, acc0, 0, 0, 0);
                acc1 = __builtin_amdgcn_mfma_f32_16x16x32_bf16(a, b1, acc1, 0, 0, 0);
            }
        }
    }
    {
        const int ch0 = lane & 15;                    // D: col=lane&15(ch), row=quad*4+r(pixel)
        const int ch1 = 16 + ch0;
        const float bias0 = boff[ch0];
        const float bias1 = (ch1 < OFFC) ? boff[ch1] : 0.f;
        #pragma unroll
        for (int r = 0; r < 4; ++r) {
            const int p = wo0 + quad * 4 + r;
            offs[p][ch0] = acc0[r] + bias0;
            if (ch1 < OFFC) offs[p][ch1] = acc1[r] + bias1;
        }
    }
    __syncthreads();

    // fold 576 taps -> gmeta
    for (int e = t; e < 64 * KK2; e += 256) {
        const int p = e / KK2, kk = e - p * KK2;
        const int wo = p;
        const float dy = offs[p][2 * kk];
        const float dx = offs[p][2 * kk + 1];
        const int ki = kk / 3, kj = kk - ki * 3;
        const float py = (float)(ho - 1 + ki) + dy;
        const float px = (float)(wo - 1 + kj) + dx;
        const float y0f = floorf(py), x0f = floorf(px);
        const int y0 = (int)y0f, x0 = (int)x0f;
        const float wy1 = py - y0f, wx1 = px - x0f;
        const float wy0 = 1.f - wy1, wx0 = 1.f - wx1;
        const int yb = min(max(y0, 0), HH - 2);
        const int zb = min(max(x0, 0), WW - 2);
        const float vy0 = ((unsigned)y0 < HH) ? wy0 : 0.f;
        const float vy1 = ((unsigned)(y0 + 1) < HH) ? wy1 : 0.f;
        const float vx0 = ((unsigned)x0 < WW) ? wx0 : 0.f;
        const float vx1 = ((unsigned)(x0 + 1) < WW) ? wx1 : 0.f;
        const float t0 = (y0 == yb ? vy0 : 0.f) + (y0 + 1 == yb ? vy1 : 0.f);
        const float t1 = (y0 == yb + 1 ? vy0 : 0.f) + (y0 + 1 == yb + 1 ? vy1 : 0.f);
        const float u0 = (x0 == zb ? vx0 : 0.f) + (x0 + 1 == zb ? vx1 : 0.f);
        const float u1 = (x0 == zb + 1 ? vx0 : 0.f) + (x0 + 1 == zb + 1 ? vx1 : 0.f);
        union { unsigned int u; _Float16 h[2]; } c0, c1;
        c0.h[0] = (_Float16)(t0 * u0); c0.h[1] = (_Float16)(t1 * u0);
        c1.h[0] = (_Float16)(t0 * u1); c1.h[1] = (_Float16)(t1 * u1);
        uint4 mt;
        mt.x = (unsigned int)((yb * 64 + zb) * 128);  // byte offset into bf16 image
        mt.y = c0.u; mt.z = c1.u; mt.w = 0u;
        gmeta[(size_t)bh * 576 + e] = mt;
    }
}

// ---------- kernel 2: gather + main GEMM ----------
__global__ __launch_bounds__(256, 7) void deform_main(const __hip_bfloat16* __restrict__ xT,
                                                      const __hip_bfloat16* __restrict__ wmp,
                                                      const float* __restrict__ bconv,
                                                      const uint4* __restrict__ gmeta,
                                                      float* __restrict__ out) {
    __shared__ __hip_bfloat16 smp[NP][SMPW];          // 18688 B; aliased as outb in epilogue
    __shared__ uint4 metal[NP * KK2];                 // 2304 B

    const int t = threadIdx.x;
    const int wave = t >> 6, lane = t & 63;
    const int sp0g = blockIdx.x * NP;
    const int b = sp0g >> 12, sp0 = sp0g & 4095;
    const char* xbB = (const char*)xT + (size_t)b * IMGB;

    if (t < NP * KK2) metal[t] = gmeta[(size_t)blockIdx.x * (NP * KK2) + t];
    __syncthreads();

    // ---- gather: 4 pixels/wave x 9 taps ----
    {
        const int li = lane & 31;
        const bool lowHalf = (lane < 32);
        for (int q = 0; q < 4; ++q) {
            const int p = wave * 4 + q;
            #pragma unroll
            for (int kk = 0; kk < KK2; ++kk) {
                const uint4 mt = metal[p * KK2 + kk]; // broadcast ds_read_b128
                const int bo = (int)mt.x;
                const unsigned int wsel = lowHalf ? mt.y : mt.z;
                union { unsigned int u; _Float16 h[2]; } cv; cv.u = wsel;
                const float tu0 = (float)cv.h[0], tu1 = (float)cv.h[1];
                // rows yb, yb+1: 256 B each = cols zb,zb+1 x 64 ch (bf16)
                const unsigned int a  = *(const unsigned int*)(xbB + bo + lane * 4);
                const unsigned int b2 = *(const unsigned int*)(xbB + bo + 8192 + lane * 4);
                const float a_lo = u2f(a << 16),  a_hi = u2f(a & 0xffff0000u);
                const float b_lo = u2f(b2 << 16), b_hi = u2f(b2 & 0xffff0000u);
                float p0 = tu0 * a_lo + tu1 * b_lo;
                float p1 = tu0 * a_hi + tu1 * b_hi;
                p0 += __shfl_xor(p0, 32, 64);         // col zb + col zb+1
                p1 += __shfl_xor(p1, 32, 64);
                if (lowHalf) {
                    __hip_bfloat162 pk;
                    pk.x = __float2bfloat16(p0);
                    pk.y = __float2bfloat16(p1);
                    *(__hip_bfloat162*)((char*)&smp[p][0] + kk * 128 + li * 4) = pk;
                }
            }
        }
    }
    __syncthreads();

    // ---- GEMM 16 x 576 @ 576 x 64; wave = 16-col N-tile ----
    f32x4 acc = {0.f, 0.f, 0.f, 0.f};
    {
        const char* abase = (const char*)&smp[lane & 15][0] + (lane >> 4) * 16;
        const short8* wp = (const short8*)wmp + wave * NKC * 64 + lane;
        #pragma unroll
        for (int kc = 0; kc < NKC; ++kc) {
            const short8 a  = *(const short8*)(abase + kc * 64);   // ds_read_b128
            const short8 bw = wp[kc * 64];                         // global, L2-hot
            acc = __builtin_amdgcn_mfma_f32_16x16x32_bf16(a, bw, acc, 0, 0, 0);
        }
    }
    __syncthreads();                                  // smp reads done; alias as outb

    // ---- epilogue via LDS for coalesced stores ----
    {
        float* outb = (float*)&smp[0][0];             // [64][17] floats = 4352 B
        const int o = wave * 16 + (lane & 15);
        const float bias = bconv[o];
        const int pr = (lane >> 4) * 4;
        #pragma unroll
        for (int r = 0; r < 4; ++r)
            outb[o * 17 + pr + r] = acc[r] + bias;
    }
    __syncthreads();
    {
        const float* outb = (const float*)&smp[0][0];
        const int oo = t >> 2, pxb = (t & 3) * 4;
        const float* lb = outb + oo * 17 + pxb;
        float4 v;
        v.x = lb[0]; v.y = lb[1]; v.z = lb[2]; v.w = lb[3];
        *(float4*)(out + ((size_t)(b * COUT + oo)) * HW + sp0 + pxb) = v;
    }
}

extern "C" void kernel_launch(void* const* d_in, const int* in_sizes, int n_in,
                              void* d_out, int out_size, void* d_ws, size_t ws_size,
                              hipStream_t stream) {
    const float* x      = (const float*)d_in[0];
    const float* w_off  = (const float*)d_in[1];
    const float* b_off  = (const float*)d_in[2];
    const float* w_conv = (const float*)d_in[3];
    const float* b_conv = (const float*)d_in[4];
    float* out = (float*)d_out;

    // ws: xT bf16 16.78MB | wmp 73728B | bop 36864B | gmeta 18.87MB  (~35.8 MB)
    __hip_bfloat16* xT  = (__hip_bfloat16*)d_ws;
    __hip_bfloat16* wmp = xT + (size_t)32 * HW * CIN;
    __hip_bfloat16* bop = wmp + 4 * NKC * 64 * 8;
    uint4* gmeta = (uint4*)((char*)d_ws + 16887808);  // 16B-aligned

    hipLaunchKernelGGL(transpose_x, dim3(32 * HH), dim3(256), 0, stream, x, xT);
    hipLaunchKernelGGL(pack_wmain,  dim3((4 * NKC * 512 + 255) / 256), dim3(256), 0, stream, w_conv, wmp);
    hipLaunchKernelGGL(pack_woff,   dim3((2 * NKC * 512 + 255) / 256), dim3(256), 0, stream, w_off, bop);
    hipLaunchKernelGGL(offset_meta, dim3(32 * HH), dim3(256), 0, stream, xT, bop, b_off, gmeta);
    hipLaunchKernelGGL(deform_main, dim3(32 * HW / NP), dim3(256), 0, stream,
                       xT, wmp, b_conv, gmeta, out);
}

// Round 5
// 170.104 us; speedup vs baseline: 3.7618x; 1.3437x over previous
//
#include <hip/hip_runtime.h>
#include <hip/hip_bf16.h>

#define CIN  64
#define COUT 64
#define HH   64
#define WW   64
#define HW   4096
#define OFFC 18
#define KK2  9
#define II   576            // CIN * KK2
#define NP   16             // pixels per block in main kernel
#define SMPW (II + 8)       // 584 bf16 -> row stride 1168 B (odd multiple of 16B)
#define NKC  (II / 32)      // 18 k-chunks for 16x16x32 MFMA
#define IMGB (HW * CIN * 2) // bytes per bf16 image = 524288

typedef __attribute__((ext_vector_type(8))) short  short8;   // 8 x bf16 (A/B frag)
typedef __attribute__((ext_vector_type(4))) float  f32x4;    // C/D frag

__device__ __forceinline__ float u2f(unsigned int u) {
    union { unsigned int i; float f; } v; v.i = u; return v.f;
}
__device__ __forceinline__ short8 as_short8(uint4 u) {
    union { uint4 a; short8 b; } v; v.a = u; return v.b;
}

// ---------- x: [B][C][H][W] f32 -> xT: [B][H][W][C] bf16 ----------
__global__ __launch_bounds__(256) void transpose_x(const float* __restrict__ x,
                                                   __hip_bfloat16* __restrict__ xT) {
    __shared__ float tile[64][65];
    const int bh = blockIdx.x;          // B*H = 2048
    const int b = bh >> 6, h = bh & 63;
    {
        const int w = threadIdx.x & 63, cg = threadIdx.x >> 6;
        #pragma unroll
        for (int c = cg; c < 64; c += 4)
            tile[c][w] = x[((b * 64 + c) * 64 + h) * 64 + w];   // coalesced over w
    }
    __syncthreads();
    {
        const int c = threadIdx.x & 63, wg = threadIdx.x >> 6;
        #pragma unroll
        for (int w = wg; w < 64; w += 4)
            xT[((b * 64 + h) * 64 + w) * 64 + c] = __float2bfloat16(tile[c][w]);
    }
}

// smp k-ordering: s = kk*64 + c. Weight packs apply matching permutation.
// ---------- combined weight pack: w_conv -> wmp (B-frag), w_offset -> bop (B-frag, 32 cols) ----------
__global__ __launch_bounds__(256) void pack_weights(const float* __restrict__ wc,
                                                    const float* __restrict__ w,
                                                    __hip_bfloat16* __restrict__ wmp,
                                                    __hip_bfloat16* __restrict__ bop) {
    const int idx = blockIdx.x * 256 + threadIdx.x;   // 36864 + 18432 = 55296
    if (idx < 4 * NKC * 64 * 8) {
        const int j    = idx & 7;
        const int lane = (idx >> 3) & 63;
        const int kc   = (idx >> 9) % NKC;
        const int nt   = idx / (NKC * 512);
        const int o  = nt * 16 + (lane & 15);
        const int ks = kc * 32 + (lane >> 4) * 8 + j;
        const int c  = ks & 63, kk = ks >> 6;
        wmp[idx] = __float2bfloat16(wc[(o * CIN + c) * KK2 + kk]);
    } else {
        const int i2 = idx - 4 * NKC * 64 * 8;        // 0..18431
        const int j    = i2 & 7;
        const int lane = (i2 >> 3) & 63;
        const int kc   = (i2 >> 9) % NKC;
        const int nt   = i2 / (NKC * 512);
        const int ch = nt * 16 + (lane & 15);
        const int ks = kc * 32 + (lane >> 4) * 8 + j;
        const int c  = ks & 63, kk = ks >> 6;
        bop[i2] = (ch < OFFC) ? __float2bfloat16(w[(ch * CIN + c) * KK2 + kk])
                              : __float2bfloat16(0.f);
    }
}

// ---------- kernel 1: offset conv (direct, MFMA from global) + folded metadata ----------
__global__ __launch_bounds__(256, 2) void offset_meta(const __hip_bfloat16* __restrict__ xT,
                                                      const __hip_bfloat16* __restrict__ bop,
                                                      const float* __restrict__ boff,
                                                      uint4* __restrict__ gmeta) {
    __shared__ float offs[64][20];                    // 5120 B
    const int t = threadIdx.x;
    const int wave = t >> 6, lane = t & 63;
    const int bh = blockIdx.x;                        // b*64 + ho
    const int b = bh >> 6, ho = bh & 63;
    const char* xbB = (const char*)xT + (size_t)b * IMGB;
    const int wo0 = wave * 16;
    const int m = lane & 15, quad = lane >> 4;

    f32x4 acc0 = {0.f, 0.f, 0.f, 0.f};               // ch 0..15
    f32x4 acc1 = {0.f, 0.f, 0.f, 0.f};               // ch 16,17
    const short8* bp = (const short8*)bop;
    #pragma unroll
    for (int ki = 0; ki < 3; ++ki) {
        const int y  = ho - 1 + ki;
        const int yl = min(max(y, 0), 63);
        const bool yok = (unsigned)y < HH;
        uint4 av[6];
        #pragma unroll
        for (int kj = 0; kj < 3; ++kj) {              // batch 6 A loads
            const int col = wo0 + m + kj - 1;
            const int ccl = min(max(col, 0), WW - 1);
            const bool ok = yok & ((unsigned)col < WW);
            const char* base = xbB + (yl * 64 + ccl) * 128 + quad * 16;
            #pragma unroll
            for (int h = 0; h < 2; ++h) {
                uint4 v = *(const uint4*)(base + h * 64);
                if (!ok) { v.x = 0u; v.y = 0u; v.z = 0u; v.w = 0u; }
                av[kj * 2 + h] = v;
            }
        }
        #pragma unroll
        for (int kj = 0; kj < 3; ++kj) {
            #pragma unroll
            for (int h = 0; h < 2; ++h) {
                const int kc = 2 * (ki * 3 + kj) + h;
                const short8 a = as_short8(av[kj * 2 + h]);
                acc0 = __builtin_amdgcn_mfma_f32_16x16x32_bf16(a, bp[kc * 64 + lane], acc0, 0, 0, 0);
                acc1 = __builtin_amdgcn_mfma_f32_16x16x32_bf16(a, bp[(NKC + kc) * 64 + lane], acc1, 0, 0, 0);
            }
        }
    }
    {
        const int ch0 = lane & 15;                    // D: col=ch, row=quad*4+r (pixel)
        const int ch1 = 16 + ch0;
        const float bias0 = boff[ch0];
        const float bias1 = (ch1 < OFFC) ? boff[ch1] : 0.f;
        #pragma unroll
        for (int r = 0; r < 4; ++r) {
            const int p = wo0 + quad * 4 + r;
            offs[p][ch0] = acc0[r] + bias0;
            if (ch1 < OFFC) offs[p][ch1] = acc1[r] + bias1;
        }
    }
    __syncthreads();

    // fold 576 taps -> gmeta
    for (int e = t; e < 64 * KK2; e += 256) {
        const int p = e / KK2, kk = e - p * KK2;
        const int wo = p;
        const float dy = offs[p][2 * kk];
        const float dx = offs[p][2 * kk + 1];
        const int ki = kk / 3, kj = kk - ki * 3;
        const float py = (float)(ho - 1 + ki) + dy;
        const float px = (float)(wo - 1 + kj) + dx;
        const float y0f = floorf(py), x0f = floorf(px);
        const int y0 = (int)y0f, x0 = (int)x0f;
        const float wy1 = py - y0f, wx1 = px - x0f;
        const float wy0 = 1.f - wy1, wx0 = 1.f - wx1;
        const int yb = min(max(y0, 0), HH - 2);
        const int zb = min(max(x0, 0), WW - 2);
        const float vy0 = ((unsigned)y0 < HH) ? wy0 : 0.f;
        const float vy1 = ((unsigned)(y0 + 1) < HH) ? wy1 : 0.f;
        const float vx0 = ((unsigned)x0 < WW) ? wx0 : 0.f;
        const float vx1 = ((unsigned)(x0 + 1) < WW) ? wx1 : 0.f;
        const float t0 = (y0 == yb ? vy0 : 0.f) + (y0 + 1 == yb ? vy1 : 0.f);
        const float t1 = (y0 == yb + 1 ? vy0 : 0.f) + (y0 + 1 == yb + 1 ? vy1 : 0.f);
        const float u0 = (x0 == zb ? vx0 : 0.f) + (x0 + 1 == zb ? vx1 : 0.f);
        const float u1 = (x0 == zb + 1 ? vx0 : 0.f) + (x0 + 1 == zb + 1 ? vx1 : 0.f);
        union { unsigned int u; _Float16 h[2]; } c0, c1;
        c0.h[0] = (_Float16)(t0 * u0); c0.h[1] = (_Float16)(t1 * u0);  // w00, w10 (col zb)
        c1.h[0] = (_Float16)(t0 * u1); c1.h[1] = (_Float16)(t1 * u1);  // w01, w11 (col zb+1)
        uint4 mt;
        mt.x = (unsigned int)((yb * 64 + zb) * 128);  // byte offset into bf16 image
        mt.y = c0.u; mt.z = c1.u; mt.w = 0u;
        gmeta[(size_t)bh * 576 + e] = mt;
    }
}

// ---------- kernel 2: gather + main GEMM ----------
__global__ __launch_bounds__(256, 6) void deform_main(const __hip_bfloat16* __restrict__ xT,
                                                      const __hip_bfloat16* __restrict__ wmp,
                                                      const float* __restrict__ bconv,
                                                      const uint4* __restrict__ gmeta,
                                                      float* __restrict__ out) {
    __shared__ __hip_bfloat16 smp[NP][SMPW];          // 18688 B; aliased as outb in epilogue
    __shared__ uint4 metal[NP * KK2];                 // 2304 B

    const int t = threadIdx.x;
    const int wave = t >> 6, lane = t & 63;
    const int sp0g = blockIdx.x * NP;
    const int b = sp0g >> 12, sp0 = sp0g & 4095;
    const char* xbB = (const char*)xT + (size_t)b * IMGB;

    if (t < NP * KK2) metal[t] = gmeta[(size_t)blockIdx.x * (NP * KK2) + t];
    __syncthreads();

    // ---- gather: 4 pixels/wave; 2 taps per iteration (one per 32-lane half), batched loads ----
    {
        const int li = lane & 31;                     // channel pair index
        const int h  = lane >> 5;                     // half -> tap select
        const char* xli = xbB + li * 4;
        for (int q = 0; q < 4; ++q) {
            const int p = wave * 4 + q;
            uint4 mtj[5];
            #pragma unroll
            for (int j = 0; j < 5; ++j) {             // 5 ds_read_b128, 2-addr broadcast
                const int kk = min(2 * j + h, 8);
                mtj[j] = metal[p * KK2 + kk];
            }
            unsigned int rg[5][4];
            #pragma unroll
            for (int j = 0; j < 5; ++j) {             // 20 global loads issued together
                const char* base = xli + (int)mtj[j].x;
                rg[j][0] = *(const unsigned int*)(base);          // row yb,   col zb
                rg[j][1] = *(const unsigned int*)(base + 128);    // row yb,   col zb+1
                rg[j][2] = *(const unsigned int*)(base + 8192);   // row yb+1, col zb
                rg[j][3] = *(const unsigned int*)(base + 8320);   // row yb+1, col zb+1
            }
            #pragma unroll
            for (int j = 0; j < 5; ++j) {
                union { unsigned int u; _Float16 f[2]; } c0, c1;
                c0.u = mtj[j].y; c1.u = mtj[j].z;
                const float w00 = (float)c0.f[0], w10 = (float)c0.f[1];
                const float w01 = (float)c1.f[0], w11 = (float)c1.f[1];
                const float a0l = u2f(rg[j][0] << 16), a0h = u2f(rg[j][0] & 0xffff0000u);
                const float a1l = u2f(rg[j][1] << 16), a1h = u2f(rg[j][1] & 0xffff0000u);
                const float b0l = u2f(rg[j][2] << 16), b0h = u2f(rg[j][2] & 0xffff0000u);
                const float b1l = u2f(rg[j][3] << 16), b1h = u2f(rg[j][3] & 0xffff0000u);
                const float vl = w00 * a0l + w01 * a1l + w10 * b0l + w11 * b1l;
                const float vh = w00 * a0h + w01 * a1h + w10 * b0h + w11 * b1h;
                const int kk = min(2 * j + h, 8);     // j==4: both halves write same data
                __hip_bfloat162 pk;
                pk.x = __float2bfloat16(vl);
                pk.y = __float2bfloat16(vh);
                *(__hip_bfloat162*)((char*)&smp[p][0] + kk * 128 + li * 4) = pk;
            }
        }
    }
    __syncthreads();

    // ---- GEMM 16 x 576 @ 576 x 64; wave = 16-col N-tile ----
    f32x4 acc = {0.f, 0.f, 0.f, 0.f};
    {
        const char* abase = (const char*)&smp[lane & 15][0] + (lane >> 4) * 16;
        const short8* wp = (const short8*)wmp + wave * NKC * 64 + lane;
        #pragma unroll
        for (int kc = 0; kc < NKC; ++kc) {
            const short8 a  = *(const short8*)(abase + kc * 64);   // ds_read_b128
            const short8 bw = wp[kc * 64];                         // global, L1/L2-hot
            acc = __builtin_amdgcn_mfma_f32_16x16x32_bf16(a, bw, acc, 0, 0, 0);
        }
    }
    __syncthreads();                                  // smp reads done; alias as outb

    // ---- epilogue via LDS for coalesced stores ----
    {
        float* outb = (float*)&smp[0][0];             // [64][17] floats = 4352 B
        const int o = wave * 16 + (lane & 15);
        const float bias = bconv[o];
        const int pr = (lane >> 4) * 4;
        #pragma unroll
        for (int r = 0; r < 4; ++r)
            outb[o * 17 + pr + r] = acc[r] + bias;
    }
    __syncthreads();
    {
        const float* outb = (const float*)&smp[0][0];
        const int oo = t >> 2, pxb = (t & 3) * 4;
        const float* lb = outb + oo * 17 + pxb;
        float4 v;
        v.x = lb[0]; v.y = lb[1]; v.z = lb[2]; v.w = lb[3];
        *(float4*)(out + ((size_t)(b * COUT + oo)) * HW + sp0 + pxb) = v;
    }
}

extern "C" void kernel_launch(void* const* d_in, const int* in_sizes, int n_in,
                              void* d_out, int out_size, void* d_ws, size_t ws_size,
                              hipStream_t stream) {
    const float* x      = (const float*)d_in[0];
    const float* w_off  = (const float*)d_in[1];
    const float* b_off  = (const float*)d_in[2];
    const float* w_conv = (const float*)d_in[3];
    const float* b_conv = (const float*)d_in[4];
    float* out = (float*)d_out;

    // ws: xT bf16 16.78MB | wmp 73728B | bop 36864B | gmeta 18.87MB  (~35.8 MB)
    __hip_bfloat16* xT  = (__hip_bfloat16*)d_ws;
    __hip_bfloat16* wmp = xT + (size_t)32 * HW * CIN;
    __hip_bfloat16* bop = wmp + 4 * NKC * 64 * 8;
    uint4* gmeta = (uint4*)((char*)d_ws + 16887808);  // 16B-aligned

    hipLaunchKernelGGL(transpose_x,  dim3(32 * HH), dim3(256), 0, stream, x, xT);
    hipLaunchKernelGGL(pack_weights, dim3(55296 / 256), dim3(256), 0, stream, w_conv, w_off, wmp, bop);
    hipLaunchKernelGGL(offset_meta,  dim3(32 * HH), dim3(256), 0, stream, xT, bop, b_off, gmeta);
    hipLaunchKernelGGL(deform_main,  dim3(32 * HW / NP), dim3(256), 0, stream,
                       xT, wmp, b_conv, gmeta, out);
}

// Round 7
// 159.409 us; speedup vs baseline: 4.0142x; 1.0671x over previous
//
#include <hip/hip_runtime.h>
#include <hip/hip_bf16.h>

#define CIN  64
#define COUT 64
#define HH   64
#define WW   64
#define HW   4096
#define OFFC 18
#define KK2  9
#define II   576            // CIN * KK2
#define NP   16             // pixels per block in main kernel
#define SMPW (II + 8)       // 584 bf16 -> row stride 1168 B (odd multiple of 16B)
#define NKC  (II / 32)      // 18 k-chunks for 16x16x32 MFMA
#define IMGB (HW * CIN * 2) // bytes per bf16 image = 524288

typedef __attribute__((ext_vector_type(8))) short  short8;   // 8 x bf16 (A/B frag)
typedef __attribute__((ext_vector_type(4))) float  f32x4;    // C/D frag

__device__ __forceinline__ float u2f(unsigned int u) {
    union { unsigned int i; float f; } v; v.i = u; return v.f;
}
__device__ __forceinline__ short8 as_short8(uint4 u) {
    union { uint4 a; short8 b; } v; v.a = u; return v.b;
}
__device__ __forceinline__ unsigned short f2bf_bits(float f) {
    union { __hip_bfloat16 b; unsigned short s; } cv;
    cv.b = __float2bfloat16(f);
    return cv.s;
}

// ---------- K1: transpose x (NCHW f32 -> NHWC bf16) + pack both weight tensors ----------
// blocks 0..2047: transpose one (b,h) row. blocks 2048..2263: weight packing.
__global__ __launch_bounds__(256) void prep(const float* __restrict__ x,
                                            const float* __restrict__ wc,
                                            const float* __restrict__ w,
                                            __hip_bfloat16* __restrict__ xT,
                                            __hip_bfloat16* __restrict__ wmp,
                                            __hip_bfloat16* __restrict__ bop) {
    const int t = threadIdx.x;
    if (blockIdx.x < 2048) {
        __shared__ float tile[64][68];                // 68: 16B-aligned float4 rows, 2-way banks
        const int b = blockIdx.x >> 6, h = blockIdx.x & 63;
        {
            const int w4 = t & 15, cg = t >> 4;       // 16 float4 chunks x 16 c-groups
            #pragma unroll
            for (int i = 0; i < 4; ++i) {
                const int c = cg + i * 16;
                const float4 v = *(const float4*)&x[((b * 64 + c) * 64 + h) * 64 + w4 * 4];
                *(float4*)&tile[c][w4 * 4] = v;       // ds_write_b128
            }
        }
        __syncthreads();
        {
            const int ww = t & 63, c0 = (t >> 6) * 16;
            unsigned int pk[8];
            #pragma unroll
            for (int ci = 0; ci < 8; ++ci) {
                const unsigned int lo = f2bf_bits(tile[c0 + 2 * ci][ww]);
                const unsigned int hi = f2bf_bits(tile[c0 + 2 * ci + 1][ww]);
                pk[ci] = lo | (hi << 16);
            }
            char* dst = (char*)xT + (size_t)(((b * 64 + h) * 64 + ww) * 64 + c0) * 2;
            uint4 v0, v1;
            v0.x = pk[0]; v0.y = pk[1]; v0.z = pk[2]; v0.w = pk[3];
            v1.x = pk[4]; v1.y = pk[5]; v1.z = pk[6]; v1.w = pk[7];
            *(uint4*)dst = v0;                        // 32 contiguous B per thread
            *(uint4*)(dst + 16) = v1;
        }
    } else {
        // smp k-ordering: s = kk*64 + c; packs apply matching permutation
        const int idx = (blockIdx.x - 2048) * 256 + t;    // 0..55295
        if (idx < 4 * NKC * 64 * 8) {
            const int j    = idx & 7;
            const int lane = (idx >> 3) & 63;
            const int kc   = (idx >> 9) % NKC;
            const int nt   = idx / (NKC * 512);
            const int o  = nt * 16 + (lane & 15);
            const int ks = kc * 32 + (lane >> 4) * 8 + j;
            const int c  = ks & 63, kk = ks >> 6;
            wmp[idx] = __float2bfloat16(wc[(o * CIN + c) * KK2 + kk]);
        } else {
            const int i2 = idx - 4 * NKC * 64 * 8;        // 0..18431
            const int j    = i2 & 7;
            const int lane = (i2 >> 3) & 63;
            const int kc   = (i2 >> 9) % NKC;
            const int nt   = i2 / (NKC * 512);
            const int ch = nt * 16 + (lane & 15);
            const int ks = kc * 32 + (lane >> 4) * 8 + j;
            const int c  = ks & 63, kk = ks >> 6;
            bop[i2] = (ch < OFFC) ? __float2bfloat16(w[(ch * CIN + c) * KK2 + kk])
                                  : __float2bfloat16(0.f);
        }
    }
}

// ---------- K2: fused offset conv (MFMA, A direct-from-global) + fold + gather + main GEMM ----------
__global__ __launch_bounds__(256, 6) void deform_fused(const __hip_bfloat16* __restrict__ xT,
                                                       const __hip_bfloat16* __restrict__ bop,
                                                       const __hip_bfloat16* __restrict__ wmp,
                                                       const float* __restrict__ boff,
                                                       const float* __restrict__ bconv,
                                                       float* __restrict__ out) {
    __shared__ __hip_bfloat16 smp[NP][SMPW];          // 18688 B; aliased: pacc+offs early, outb late
    __shared__ uint4 metal[NP * KK2];                 // 2304 B

    const int t = threadIdx.x;
    const int wave = t >> 6, lane = t & 63;
    const int sp0g = blockIdx.x * NP;
    const int b = sp0g >> 12, sp0 = sp0g & 4095;
    const int ho = sp0 >> 6, wo0 = sp0 & 63;          // NP=16 divides 64 -> row-uniform block
    const char* xbB = (const char*)xT + (size_t)b * IMGB;

    // ---- phase 1: offset conv partials; taps split across waves; A-frag from global ----
    f32x4 acc0 = {0.f, 0.f, 0.f, 0.f};               // ch 0..15
    f32x4 acc1 = {0.f, 0.f, 0.f, 0.f};               // ch 16,17
    {
        const int m = lane & 15, quad = lane >> 4;
        const short8* bp = (const short8*)bop;
        for (int kk = wave; kk < KK2; kk += 4) {      // wave0: {0,4,8}, w1:{1,5}, w2:{2,6}, w3:{3,7}
            const int ki = kk / 3, kj = kk - ki * 3;
            const int y = ho - 1 + ki;                // wave-uniform
            if ((unsigned)y < HH) {
                const int col = wo0 + m + kj - 1;
                const int ccl = min(max(col, 0), WW - 1);
                const bool ok = (unsigned)col < WW;
                const char* base = xbB + (y * 64 + ccl) * 128 + quad * 16;
                uint4 v0 = *(const uint4*)(base);     // ch quad*8..+7 (low half)
                uint4 v1 = *(const uint4*)(base + 64);// high half
                if (!ok) { v0.x = v0.y = v0.z = v0.w = 0u; v1.x = v1.y = v1.z = v1.w = 0u; }
                const int kc0 = 2 * kk, kc1 = 2 * kk + 1;
                acc0 = __builtin_amdgcn_mfma_f32_16x16x32_bf16(as_short8(v0), bp[kc0 * 64 + lane], acc0, 0, 0, 0);
                acc1 = __builtin_amdgcn_mfma_f32_16x16x32_bf16(as_short8(v0), bp[(NKC + kc0) * 64 + lane], acc1, 0, 0, 0);
                acc0 = __builtin_amdgcn_mfma_f32_16x16x32_bf16(as_short8(v1), bp[kc1 * 64 + lane], acc0, 0, 0, 0);
                acc1 = __builtin_amdgcn_mfma_f32_16x16x32_bf16(as_short8(v1), bp[(NKC + kc1) * 64 + lane], acc1, 0, 0, 0);
            }
        }
        // store wave partials: pacc[4][16 px][20 ch] aliases smp
        float* pacc = (float*)&smp[0][0];
        const int n = lane & 15;
        #pragma unroll
        for (int r = 0; r < 4; ++r) {
            const int p = quad * 4 + r;               // D: col=ch, row=quad*4+r (pixel)
            pacc[(wave * 16 + p) * 20 + n] = acc0[r];
            if (n < 2) pacc[(wave * 16 + p) * 20 + 16 + n] = acc1[r];
        }
    }
    __syncthreads();

    // ---- phase 2: reduce partials + bias -> offs[16][20] (aliases smp after pacc) ----
    {
        float* pacc = (float*)&smp[0][0];
        float* offs = pacc + 4 * 16 * 20;
        for (int e = t; e < NP * OFFC; e += 256) {
            const int p = e / OFFC, ch = e - p * OFFC;
            offs[p * 20 + ch] = boff[ch]
                + pacc[p * 20 + ch] + pacc[(16 + p) * 20 + ch]
                + pacc[(32 + p) * 20 + ch] + pacc[(48 + p) * 20 + ch];
        }
    }
    __syncthreads();

    // ---- phase 3: fold 144 taps -> metal ----
    if (t < NP * KK2) {
        const float* offs = (const float*)&smp[0][0] + 4 * 16 * 20;
        const int p = t / KK2, kk = t - p * KK2;
        const int wo = wo0 + p;
        const float dy = offs[p * 20 + 2 * kk];
        const float dx = offs[p * 20 + 2 * kk + 1];
        const int ki = kk / 3, kj = kk - ki * 3;
        const float py = (float)(ho - 1 + ki) + dy;
        const float px = (float)(wo - 1 + kj) + dx;
        const float y0f = floorf(py), x0f = floorf(px);
        const int y0 = (int)y0f, x0 = (int)x0f;
        const float wy1 = py - y0f, wx1 = px - x0f;
        const float wy0 = 1.f - wy1, wx0 = 1.f - wx1;
        const int yb = min(max(y0, 0), HH - 2);
        const int zb = min(max(x0, 0), WW - 2);
        const float vy0 = ((unsigned)y0 < HH) ? wy0 : 0.f;
        const float vy1 = ((unsigned)(y0 + 1) < HH) ? wy1 : 0.f;
        const float vx0 = ((unsigned)x0 < WW) ? wx0 : 0.f;
        const float vx1 = ((unsigned)(x0 + 1) < WW) ? wx1 : 0.f;
        const float t0 = (y0 == yb ? vy0 : 0.f) + (y0 + 1 == yb ? vy1 : 0.f);
        const float t1 = (y0 == yb + 1 ? vy0 : 0.f) + (y0 + 1 == yb + 1 ? vy1 : 0.f);
        const float u0 = (x0 == zb ? vx0 : 0.f) + (x0 + 1 == zb ? vx1 : 0.f);
        const float u1 = (x0 == zb + 1 ? vx0 : 0.f) + (x0 + 1 == zb + 1 ? vx1 : 0.f);
        union { unsigned int u; _Float16 h[2]; } c0, c1;
        c0.h[0] = (_Float16)(t0 * u0); c0.h[1] = (_Float16)(t1 * u0);  // w00, w10 (col zb)
        c1.h[0] = (_Float16)(t0 * u1); c1.h[1] = (_Float16)(t1 * u1);  // w01, w11 (col zb+1)
        uint4 mt;
        mt.x = (unsigned int)((yb * 64 + zb) * 128);  // byte offset into bf16 image
        mt.y = c0.u; mt.z = c1.u; mt.w = 0u;
        metal[t] = mt;
    }
    __syncthreads();

    // ---- phase 4: gather (4 px/wave, 2 taps/iter, batched loads) -> smp (overwrites pacc/offs) ----
    {
        const int li = lane & 31;                     // channel pair index
        const int h  = lane >> 5;                     // half -> tap select
        const char* xli = xbB + li * 4;
        for (int q = 0; q < 4; ++q) {
            const int p = wave * 4 + q;
            uint4 mtj[5];
            #pragma unroll
            for (int j = 0; j < 5; ++j) {             // 5 ds_read_b128, 2-addr broadcast
                const int kk = min(2 * j + h, 8);
                mtj[j] = metal[p * KK2 + kk];
            }
            unsigned int rg[5][4];
            #pragma unroll
            for (int j = 0; j < 5; ++j) {             // 20 global loads issued together
                const char* base = xli + (int)mtj[j].x;
                rg[j][0] = *(const unsigned int*)(base);          // row yb,   col zb
                rg[j][1] = *(const unsigned int*)(base + 128);    // row yb,   col zb+1
                rg[j][2] = *(const unsigned int*)(base + 8192);   // row yb+1, col zb
                rg[j][3] = *(const unsigned int*)(base + 8320);   // row yb+1, col zb+1
            }
            #pragma unroll
            for (int j = 0; j < 5; ++j) {
                union { unsigned int u; _Float16 f[2]; } c0, c1;
                c0.u = mtj[j].y; c1.u = mtj[j].z;
                const float w00 = (float)c0.f[0], w10 = (float)c0.f[1];
                const float w01 = (float)c1.f[0], w11 = (float)c1.f[1];
                const float a0l = u2f(rg[j][0] << 16), a0h = u2f(rg[j][0] & 0xffff0000u);
                const float a1l = u2f(rg[j][1] << 16), a1h = u2f(rg[j][1] & 0xffff0000u);
                const float b0l = u2f(rg[j][2] << 16), b0h = u2f(rg[j][2] & 0xffff0000u);
                const float b1l = u2f(rg[j][3] << 16), b1h = u2f(rg[j][3] & 0xffff0000u);
                const float vl = w00 * a0l + w01 * a1l + w10 * b0l + w11 * b1l;
                const float vh = w00 * a0h + w01 * a1h + w10 * b0h + w11 * b1h;
                const int kk = min(2 * j + h, 8);     // j==4: both halves write same data
                __hip_bfloat162 pk;
                pk.x = __float2bfloat16(vl);
                pk.y = __float2bfloat16(vh);
                *(__hip_bfloat162*)((char*)&smp[p][0] + kk * 128 + li * 4) = pk;
            }
        }
    }
    __syncthreads();

    // ---- phase 5: main GEMM 16 x 576 @ 576 x 64; wave = 16-col N-tile ----
    f32x4 acc = {0.f, 0.f, 0.f, 0.f};
    {
        const char* abase = (const char*)&smp[lane & 15][0] + (lane >> 4) * 16;
        const short8* wp = (const short8*)wmp + wave * NKC * 64 + lane;
        #pragma unroll
        for (int kc = 0; kc < NKC; ++kc) {
            const short8 a  = *(const short8*)(abase + kc * 64);   // ds_read_b128
            const short8 bw = wp[kc * 64];                         // global, L1/L2-hot
            acc = __builtin_amdgcn_mfma_f32_16x16x32_bf16(a, bw, acc, 0, 0, 0);
        }
    }
    __syncthreads();                                  // smp reads done; alias as outb

    // ---- phase 6: epilogue via LDS for coalesced stores ----
    {
        float* outb = (float*)&smp[0][0];             // [64][17] floats = 4352 B
        const int o = wave * 16 + (lane & 15);
        const float bias = bconv[o];
        const int pr = (lane >> 4) * 4;
        #pragma unroll
        for (int r = 0; r < 4; ++r)
            outb[o * 17 + pr + r] = acc[r] + bias;
    }
    __syncthreads();
    {
        const float* outb = (const float*)&smp[0][0];
        const int oo = t >> 2, pxb = (t & 3) * 4;
        const float* lb = outb + oo * 17 + pxb;
        float4 v;
        v.x = lb[0]; v.y = lb[1]; v.z = lb[2]; v.w = lb[3];
        *(float4*)(out + ((size_t)(b * COUT + oo)) * HW + sp0 + pxb) = v;
    }
}

extern "C" void kernel_launch(void* const* d_in, const int* in_sizes, int n_in,
                              void* d_out, int out_size, void* d_ws, size_t ws_size,
                              hipStream_t stream) {
    const float* x      = (const float*)d_in[0];
    const float* w_off  = (const float*)d_in[1];
    const float* b_off  = (const float*)d_in[2];
    const float* w_conv = (const float*)d_in[3];
    const float* b_conv = (const float*)d_in[4];
    float* out = (float*)d_out;

    // ws: xT bf16 16.78MB | wmp 73728B | bop 36864B
    __hip_bfloat16* xT  = (__hip_bfloat16*)d_ws;
    __hip_bfloat16* wmp = xT + (size_t)32 * HW * CIN;
    __hip_bfloat16* bop = wmp + 4 * NKC * 64 * 8;

    hipLaunchKernelGGL(prep, dim3(2048 + 216), dim3(256), 0, stream,
                       x, w_conv, w_off, xT, wmp, bop);
    hipLaunchKernelGGL(deform_fused, dim3(32 * HW / NP), dim3(256), 0, stream,
                       xT, bop, wmp, b_off, b_conv, out);
}